// Round 1
// 91.247 us; speedup vs baseline: 1.0154x; 1.0154x over previous
//
#include <hip/hip_runtime.h>

// Bilateral 5x5, sigma_spatial=1.5, sigma_color=0.1, reflect pad.
// [2,3,1024,1024] fp32 = 6 independent 1024x1024 images.
//
// Schraudolph magic-window weights (no cvt, no transcendental):
//   tile pre-scaled by S13 = sqrt(2^13*50*log2(e));
//   t = fma(-u,u,Cij), Cij = 12582912 + 2^13*(127-0.043+lk2_ij)
//   t in [2^23,2^24): bits(t) = 0x4B400000 + s; w = bitcast(bits<<10).
// R6: taps packed in float2 along j ({0,1},{2,3} pairs): v_pk ops + ONE
//   v_lshlrev_b64 decodes BOTH packed weights (high word gains +0x3FF max
//   in low mantissa bits = ~1.2e-4 rel, negligible vs 3.9e-3 threshold).
// R7 (this round):
//   - j=4 column packed ACROSS the two pixels of a q-step: circular pair
//     window P[k] = {col4[row k], col4[row k+1]} makes the last scalar
//     column ride the packed pipe too (inner loop 150 -> 125 instr).
//   - TY 64->32 (RPT 8): 3072 blocks = 12/CU for latency hiding + tail.
//   - q-steps hand-unrolled via STEP(Q) macro with literal indices:
//     register window can never fall to scratch.
// Center tap (2,2) rides the packed pipe approximately; exact value
// restored via constant accumulator-init bias CORR = K2C - W22.

#define TX 64
#define TY 32
#define BY 4
#define RPT (TY / BY)     // 8 output rows per thread
#define PAD 2
#define LW (TX + 2 * PAD) // 68
#define LH (TY + 2 * PAD) // 36

typedef float f2 __attribute__((ext_vector_type(2)));

__device__ __forceinline__ f2 decode2(f2 t) {
    unsigned long long b = __builtin_bit_cast(unsigned long long, t);
    return __builtin_bit_cast(f2, b << 10);
}
__device__ __forceinline__ float decode1(float t) {
    return __builtin_bit_cast(float, __builtin_bit_cast(unsigned, t) << 10);
}

__global__ __launch_bounds__(256) void bilateral_kernel(
    const float* __restrict__ in, float* __restrict__ out, int H, int W)
{
    const int z  = blockIdx.z;
    const int x0 = blockIdx.x * TX;
    const int y0 = blockIdx.y * TY;
    const int tx = threadIdx.x;
    const int ty = threadIdx.y;
    const int tid = ty * TX + tx;

    // S13 = sqrt(2^13 * 50 * log2(e));  SEPS = S13 * 1e-8
    const float S13  = 768.744433f;
    const float SEPS = 7.68744433e-6f;

    __shared__ float tile[LH * LW];
    const float* img = in + (size_t)z * H * W;

    // Cooperative halo load (reflect, pad=2), pre-scaled by S13.
    for (int idx = tid; idx < LH * LW; idx += TX * BY) {
        int r = idx / LW;
        int c = idx - r * LW;
        int gy = y0 - PAD + r;
        int gx = x0 - PAD + c;
        gy = gy < 0 ? -gy : (gy >= H ? 2 * H - 2 - gy : gy);
        gx = gx < 0 ? -gx : (gx >= W ? 2 * W - 2 - gx : gx);
        tile[idx] = img[(size_t)gy * W + gx] * S13;
    }
    __syncthreads();

    // log2 of normalized 1-D spatial gaussian (sigma=1.5, k=5).
    constexpr double Ld[5] = {-3.0580100, -2.0962162, -1.7756103,
                              -2.0962162, -3.0580100};
    constexpr double A13   = 8192.0;               // 2^13
    constexpr double CMAG  = 12582912.0 + (127.0 - 0.043) * 8192.0;
#define CD(i, j) ((float)(CMAG + A13 * (Ld[i] + Ld[j])))

    const float K2C  = 0.0853118f;                 // exact center weight
    const float W22  = decode1(CD(2, 2));          // schraudolph center (folds)
    const float CORR = K2C - W22;                  // accumulator-init bias

    const int ly0 = ty * RPT;

    // 6-row circular register window as j-pairs:
    // wA = cols {tx,tx+1} (j=0,1), wB = {tx+2,tx+3} (j=2,3).
    // P[k] = {col4[row k], col4[row k+1]}  (packed-across-pixels j=4 column).
    f2 wA[6], wB[6], P[6];
    {
        float c4v[4];
#pragma unroll
        for (int r = 0; r < 4; ++r) {
            const int o = (ly0 + r) * LW + tx;
            wA[r]  = f2{tile[o],     tile[o + 1]};
            wB[r]  = f2{tile[o + 2], tile[o + 3]};
            c4v[r] = tile[o + 4];
        }
        P[0] = f2{c4v[0], c4v[1]};
        P[1] = f2{c4v[1], c4v[2]};
        P[2] = f2{c4v[2], c4v[3]};
    }

#define STEP(Q)                                                               \
    {                                                                         \
        float c4n, c5n;                                                       \
        {                                                                     \
            const int o = (ly0 + (Q) + 4) * LW + tx;                          \
            wA[((Q) + 4) % 6] = f2{tile[o],     tile[o + 1]};                 \
            wB[((Q) + 4) % 6] = f2{tile[o + 2], tile[o + 3]};                 \
            c4n = tile[o + 4];                                                \
        }                                                                     \
        {                                                                     \
            const int o = (ly0 + (Q) + 5) * LW + tx;                          \
            wA[((Q) + 5) % 6] = f2{tile[o],     tile[o + 1]};                 \
            wB[((Q) + 5) % 6] = f2{tile[o + 2], tile[o + 3]};                 \
            c5n = tile[o + 4];                                                \
        }                                                                     \
        P[((Q) + 3) % 6] = f2{P[((Q) + 2) % 6].y, c4n};                       \
        P[((Q) + 4) % 6] = f2{c4n, c5n};                                      \
        const float c0 = wB[((Q) + 2) % 6].x;   /* scaled centers (j=2) */    \
        const float c1 = wB[((Q) + 3) % 6].x;                                 \
        const f2 cP = f2{c0, c1};                                             \
        f2 ws0 = f2{CORR, 0.f}, vs0 = f2{CORR * c0, 0.f};                     \
        f2 ws1 = f2{CORR, 0.f}, vs1 = f2{CORR * c1, 0.f};                     \
        f2 wtP = f2{0.f, 0.f},  vtP = f2{0.f, 0.f};                           \
        _Pragma("unroll")                                                     \
        for (int i = 0; i < 5; ++i) {                                         \
            const int r0 = ((Q) + i) % 6;                                     \
            const int r1 = ((Q) + 1 + i) % 6;                                 \
            const f2 CA = f2{CD(i, 0), CD(i, 1)};                             \
            const f2 CB = f2{CD(i, 2), CD(i, 3)};                             \
            const f2 C4 = f2{CD(i, 4), CD(i, 4)};                             \
            { /* ---- pixel 0, cols j=0..3 ---- */                            \
                const f2 c2 = f2{c0, c0};                                     \
                f2 u = wA[r0] - c2;                                           \
                f2 w = decode2(__builtin_elementwise_fma(-u, u, CA));         \
                ws0 += w; vs0 = __builtin_elementwise_fma(w, wA[r0], vs0);    \
                u = wB[r0] - c2;                                              \
                w = decode2(__builtin_elementwise_fma(-u, u, CB));            \
                ws0 += w; vs0 = __builtin_elementwise_fma(w, wB[r0], vs0);    \
            }                                                                 \
            { /* ---- pixel 1, cols j=0..3 ---- */                            \
                const f2 c2 = f2{c1, c1};                                     \
                f2 u = wA[r1] - c2;                                           \
                f2 w = decode2(__builtin_elementwise_fma(-u, u, CA));         \
                ws1 += w; vs1 = __builtin_elementwise_fma(w, wA[r1], vs1);    \
                u = wB[r1] - c2;                                              \
                w = decode2(__builtin_elementwise_fma(-u, u, CB));            \
                ws1 += w; vs1 = __builtin_elementwise_fma(w, wB[r1], vs1);    \
            }                                                                 \
            { /* ---- col j=4, both pixels packed ---- */                     \
                const f2 pv = P[r0];                                          \
                f2 u = pv - cP;                                               \
                f2 w = decode2(__builtin_elementwise_fma(-u, u, C4));         \
                wtP += w; vtP = __builtin_elementwise_fma(w, pv, vtP);        \
            }                                                                 \
        }                                                                     \
        const float w0 = (ws0.x + ws0.y) + wtP.x;                             \
        const float v0 = (vs0.x + vs0.y) + vtP.x;                             \
        const float w1 = (ws1.x + ws1.y) + wtP.y;                             \
        const float v1 = (vs1.x + vs1.y) + vtP.y;                             \
        const float r0v = __builtin_amdgcn_rcpf(__builtin_fmaf(S13, w0, SEPS)); \
        const float r1v = __builtin_amdgcn_rcpf(__builtin_fmaf(S13, w1, SEPS)); \
        const size_t base = ((size_t)z * H + (y0 + ly0 + (Q))) * W + (x0 + tx); \
        out[base]     = v0 * r0v;                                             \
        out[base + W] = v1 * r1v;                                             \
    }

    STEP(0)
    STEP(2)
    STEP(4)
    STEP(6)

#undef STEP
#undef CD
}

extern "C" void kernel_launch(void* const* d_in, const int* in_sizes, int n_in,
                              void* d_out, int out_size, void* d_ws, size_t ws_size,
                              hipStream_t stream) {
    const float* img = (const float*)d_in[0];
    float* out = (float*)d_out;

    const int B = 2, C = 3, H = 1024, W = 1024;
    dim3 block(TX, BY, 1);
    dim3 grid(W / TX, H / TY, B * C);   // 16 x 32 x 6 = 3072 blocks
    bilateral_kernel<<<grid, block, 0, stream>>>(img, out, H, W);
}